// Round 12
// baseline (166.321 us; speedup 1.0000x reference)
//
#include <hip/hip_runtime.h>
#include <hip/hip_bf16.h>
#include <cstdint>
#include <cstddef>

// Problem dims (fixed by the reference).
#define M_DIM 8192
#define K_DIM 2048
#define N_DIM 2048

// i8 GEMM config (R12): 128x128 tile, BK=64, 4 waves (2Mx2N), wave-tile 64x64,
// grid 1024 = 4 blocks/CU (occupancy lever; R11 showed 2/CU leaves every
// wait exposed). mfma_i32_32x32x32_i8: A/B 4 VGPR, C/D 16 i32.
// Fragment-major operand layout (prep kernels):
//   A_fm[m_frag(256)][k_tile(64)][lane(64)][16B], frag elem: row=l&31,
//   k = kt*32 + (l>>5)*16 + j.  Same for B (wt_fm, 64 n_frags).
// All gl_lds and ds_reads lane-linear -> zero bank conflicts, no swizzle.

typedef int i32x4 __attribute__((ext_vector_type(4)));
typedef int i32x16 __attribute__((ext_vector_type(16)));

// ws layout (bytes)
#define AFM_OFF   0u
#define WFM_OFF   16777216u   // 16 MiB
#define SCL_OFF   20971520u   // +4 MiB
#define SCLI_OFF  21004288u   // +32 KiB

__device__ __forceinline__ int clamp_rne(float v, float si) {
  int q = (int)rintf(v * si);
  q = q > 127 ? 127 : (q < -127 ? -127 : q);
  return q & 255;
}

__device__ __forceinline__ int pack4(float a, float b, float c, float d,
                                     float si) {
  return clamp_rne(a, si) | (clamp_rne(b, si) << 8) |
         (clamp_rne(c, si) << 16) | (clamp_rne(d, si) << 24);
}

// ---------------------------------------------------------------------------
// prep1: blocks [0,2048): per-row absmax, one wave per row (coalesced 1 KB
//        wave-loads, shfl_xor tree).  Side effect: x becomes L3-resident.
//        blocks [2048,2560): w (f32 [K,N]) -> wt_fm (i8 frag-major), LDS tile.
// UNCHANGED vs R11.
// ---------------------------------------------------------------------------
__global__ void prep1_kernel(const float* __restrict__ x,
                             float* __restrict__ scales,
                             float* __restrict__ scales_inv,
                             const float* __restrict__ w,
                             signed char* __restrict__ wt_fm) {
  __shared__ float wlds[32][256];  // 32 KiB (w-pack branch only)
  const int tid = threadIdx.x;
  if (blockIdx.x < 2048) {
    const int l = tid & 63;
    const int row = blockIdx.x * 4 + (tid >> 6);  // wave -> row
    const float4* xr = (const float4*)(x + (size_t)row * K_DIM);
    float m = 0.f;
#pragma unroll
    for (int i = 0; i < 8; ++i) {
      const float4 v = xr[i * 64 + l];  // 64 lanes x 16B consecutive
      m = fmaxf(m, fmaxf(fmaxf(fabsf(v.x), fabsf(v.y)),
                         fmaxf(fabsf(v.z), fabsf(v.w))));
    }
#pragma unroll
    for (int off = 32; off >= 1; off >>= 1) m = fmaxf(m, __shfl_xor(m, off));
    if (l == 0) {
      scales[row] = m * (1.f / 127.f);
      scales_inv[row] = 127.f / fmaxf(m, 1e-20f);
    }
  } else {
    // w-pack: block covers k-tile kb (32 k-rows) x 256 n-cols. Coalesced both
    // global sides; LDS reads conflict-free (lane-consecutive addresses).
    const int b = blockIdx.x - 2048;  // 0..511
    const int bn = b & 7;             // n-col block (256 each)
    const int kb = b >> 3;            // k-tile 0..63
    for (int r = 0; r < 32; ++r)
      wlds[r][tid] = w[(size_t)(kb * 32 + r) * N_DIM + bn * 256 + tid];
    __syncthreads();
    const int l = tid & 63;
    const int h16 = (l >> 5) * 16;
    const int col = (l & 31);
#pragma unroll
    for (int g = 0; g < 2; ++g) {
      const int nfl = g * 4 + (tid >> 6);  // 0..7
      const float* src = &wlds[0][0] + nfl * 32 + col;
      i32x4 out;
#pragma unroll
      for (int q = 0; q < 4; ++q) {
        out[q] = pack4(src[(h16 + q * 4 + 0) * 256], src[(h16 + q * 4 + 1) * 256],
                       src[(h16 + q * 4 + 2) * 256], src[(h16 + q * 4 + 3) * 256],
                       1.f);
      }
      *(i32x4*)(wt_fm + (size_t)(bn * 8 + nfl) * 65536 + (size_t)kb * 1024 +
                l * 16) = out;
    }
  }
}

// ---------------------------------------------------------------------------
// prep2: x -> A_fm (i8 fragment-major) via LDS tile.  UNCHANGED vs R11.
// ---------------------------------------------------------------------------
__global__ void prep2_kernel(const float* __restrict__ x,
                             const float* __restrict__ scales_inv,
                             signed char* __restrict__ a_fm) {
  __shared__ float t[32][257];
  const int tid = threadIdx.x;
  const int mf = blockIdx.x >> 3;  // 0..255
  const int kb = blockIdx.x & 7;   // 0..7
  const int c4 = tid & 63;
#pragma unroll
  for (int rr = 0; rr < 8; ++rr) {
    const int row = rr * 4 + (tid >> 6);
    const float4 v = *(const float4*)(x + (size_t)(mf * 32 + row) * K_DIM +
                                      kb * 256 + c4 * 4);
    t[row][c4 * 4 + 0] = v.x;
    t[row][c4 * 4 + 1] = v.y;
    t[row][c4 * 4 + 2] = v.z;
    t[row][c4 * 4 + 3] = v.w;
  }
  __syncthreads();
#pragma unroll
  for (int g = 0; g < 2; ++g) {
    const int c = g * 256 + tid;      // 0..511
    const int l = c & 63;
    const int ktl = c >> 6;           // 0..7
    const int row = l & 31;
    const int k0 = ktl * 32 + (l >> 5) * 16;
    const float si = scales_inv[mf * 32 + row];
    i32x4 out;
#pragma unroll
    for (int q = 0; q < 4; ++q) {
      out[q] = pack4(t[row][k0 + q * 4 + 0], t[row][k0 + q * 4 + 1],
                     t[row][k0 + q * 4 + 2], t[row][k0 + q * 4 + 3], si);
    }
    *(i32x4*)(a_fm + ((size_t)(mf * 64 + kb * 8 + ktl) * 64 + l) * 16) = out;
  }
}

// ---------------------------------------------------------------------------
// GEMM i8: C[M,N] f32 = (A_q i8) x (W_q i8)^T * scale_row.
// 1024 blocks (4/CU), 256 threads (4 waves 2x2), LDS 32 KiB dbuf.
// ---------------------------------------------------------------------------
__device__ __forceinline__ void async_copy16(signed char* lds_dst,
                                             const signed char* g_src) {
  __builtin_amdgcn_global_load_lds(
      (__attribute__((address_space(1))) void*)g_src,
      (__attribute__((address_space(3))) void*)lds_dst,
      16, 0, 0);
}

#define BARR() __builtin_amdgcn_s_barrier()
#define LGKM0()                                       \
  asm volatile("s_waitcnt lgkmcnt(0)" ::: "memory");  \
  __builtin_amdgcn_sched_barrier(0)
#define PRIO(p) __builtin_amdgcn_s_setprio(p)
#define VMCNT(n) asm volatile("s_waitcnt vmcnt(" #n ")" ::: "memory")

// Stage K-tile t (A 8 KiB + B 8 KiB) into buf t&1: 4 x gl_lds(16B)/thread.
// Chunk c of region = [mf|nf (4)][kt (2)]: c -> frag c>>1, kt c&1.
// Thread covers chunks wv and wv+4 of each region.
#define STG4(t)                                                              \
  do {                                                                       \
    signed char* _bA = smem + ((t) & 1) * 16384;                             \
    signed char* _bB = _bA + 8192;                                           \
    const size_t _k0 = (size_t)(2 * (t)) * 1024 + (wv & 1) * 1024;           \
    async_copy16(_bA + wv * 1024 + l16,                                      \
                 Afm + (size_t)(bm4 + (wv >> 1)) * 65536 + _k0 + l16);       \
    async_copy16(_bA + wv * 1024 + 4096 + l16,                               \
                 Afm + (size_t)(bm4 + (wv >> 1) + 2) * 65536 + _k0 + l16);   \
    async_copy16(_bB + wv * 1024 + l16,                                      \
                 Bfm + (size_t)(bn4 + (wv >> 1)) * 65536 + _k0 + l16);       \
    async_copy16(_bB + wv * 1024 + 4096 + l16,                               \
                 Bfm + (size_t)(bn4 + (wv >> 1) + 2) * 65536 + _k0 + l16);   \
  } while (0)

// Read the wave's 8 fragments (lane-linear, conflict-free).
#define RDT(buf)                                                             \
  do {                                                                       \
    const signed char* _bA = smem + (buf) * 16384;                           \
    const signed char* _bB = _bA + 8192;                                     \
    _Pragma("unroll") for (int nfi = 0; nfi < 2; ++nfi)                      \
      _Pragma("unroll") for (int kt = 0; kt < 2; ++kt)                       \
        bfr[nfi][kt] = *(const i32x4*)(_bB + ((wn2 + nfi) * 2 + kt) * 1024 + \
                                       l16);                                 \
    _Pragma("unroll") for (int mfi = 0; mfi < 2; ++mfi)                      \
      _Pragma("unroll") for (int kt = 0; kt < 2; ++kt)                       \
        afr[mfi][kt] = *(const i32x4*)(_bA + ((wm2 + mfi) * 2 + kt) * 1024 + \
                                       l16);                                 \
  } while (0)

#define MMT()                                                                \
  do {                                                                       \
    _Pragma("unroll") for (int mfi = 0; mfi < 2; ++mfi)                      \
      _Pragma("unroll") for (int nfi = 0; nfi < 2; ++nfi)                    \
        _Pragma("unroll") for (int kt = 0; kt < 2; ++kt)                     \
          acc[mfi][nfi] = __builtin_amdgcn_mfma_i32_32x32x32_i8(             \
              afr[mfi][kt], bfr[nfi][kt], acc[mfi][nfi], 0, 0, 0);           \
  } while (0)

__global__ __launch_bounds__(256, 4) void gemm_kernel(
    const signed char* __restrict__ Afm,  // i8 fragment-major [256][64][1024B]
    const signed char* __restrict__ Bfm,  // i8 fragment-major [64][64][1024B]
    const float* __restrict__ scales,     // [M] rowabsmax/127
    float* __restrict__ C) {              // f32 [M,N]
  __shared__ signed char smem[2 * 16384];  // 32 KiB
  __shared__ float scale_lds[128];

  const int tid = threadIdx.x;
  const int l = tid & 63;
  const int l16 = l * 16;
  const int wv = tid >> 6;        // 0..3
  const int wm2 = (wv >> 1) * 2;  // A frag base (mf units)
  const int wn2 = (wv & 1) * 2;   // B frag base (nf units)

  // XCD-aware swizzle: nwg=1024, 128 per XCD; same-bm neighbors share A panel.
  const int bid = blockIdx.x;
  const int wgid = (bid & 7) * 128 + (bid >> 3);
  const int bm = wgid >> 4;   // 0..63
  const int bn = wgid & 15;   // 0..15
  const int bm4 = bm * 4;     // A m_frag base
  const int bn4 = bn * 4;     // B n_frag base
  const int m0 = bm * 128;
  const int n0 = bn * 128;

  if (tid < 128) scale_lds[tid] = scales[m0 + tid];

  i32x16 acc[2][2] = {};
  i32x4 afr[2][2], bfr[2][2];

  STG4(0);
  STG4(1);
  VMCNT(4);  // tile0 arrived (tile1's 4 in flight)
  BARR();

#pragma unroll 1
  for (int j = 0; j < 15; ++j) {
    const int e = 2 * j;
    // tile e (buf0)
    RDT(0);
    LGKM0();
    PRIO(1); MMT(); PRIO(0);
    BARR();           // WAR: buf0 consumed
    STG4(e + 2);
    VMCNT(4);         // drain tile e+1's loads (e+2's 4 remain)
    BARR();           // publish tile e+1
    // tile e+1 (buf1)
    RDT(1);
    LGKM0();
    PRIO(1); MMT(); PRIO(0);
    BARR();           // WAR: buf1 consumed
    STG4(e + 3);
    VMCNT(4);         // drain tile e+2's loads
    BARR();           // publish tile e+2
  }
  // tile 30 (buf0): no restage; publish tile 31.
  RDT(0);
  LGKM0();
  PRIO(1); MMT(); PRIO(0);
  BARR();
  VMCNT(0);
  BARR();
  // tile 31 (buf1): final.
  RDT(1);
  LGKM0();
  PRIO(1); MMT(); PRIO(0);

  // Epilogue: C/D 32x32 layout col=lane&31, row=(reg&3)+8*(reg>>2)+4*(lane>>5).
  const int colb = n0 + (wv & 1) * 64 + (l & 31);
  const int rowb = (wv >> 1) * 64 + 4 * (l >> 5);
#pragma unroll
  for (int mfi = 0; mfi < 2; ++mfi) {
#pragma unroll
    for (int nfi = 0; nfi < 2; ++nfi) {
      const int col = colb + nfi * 32;
#pragma unroll
      for (int r = 0; r < 16; ++r) {
        const int lrow = rowb + mfi * 32 + (r & 3) + 8 * (r >> 2);
        C[(size_t)(m0 + lrow) * N_DIM + col] =
            (float)acc[mfi][nfi][r] * scale_lds[lrow];
      }
    }
  }
}

// ---------------------------------------------------------------------------
extern "C" void kernel_launch(void* const* d_in, const int* in_sizes, int n_in,
                              void* d_out, int out_size, void* d_ws,
                              size_t ws_size, hipStream_t stream) {
  const float* x = (const float*)d_in[0];  // [M,K] f32
  const float* w = (const float*)d_in[1];  // [K,N] f32
  float* out = (float*)d_out;              // [M,N] f32

  signed char* a_fm = (signed char*)d_ws + AFM_OFF;
  signed char* wt_fm = (signed char*)d_ws + WFM_OFF;
  float* scales = (float*)((char*)d_ws + SCL_OFF);
  float* scales_inv = (float*)((char*)d_ws + SCLI_OFF);

  prep1_kernel<<<2560, 256, 0, stream>>>(x, scales, scales_inv, w, wt_fm);
  prep2_kernel<<<2048, 256, 0, stream>>>(x, scales_inv, a_fm);
  gemm_kernel<<<1024, 256, 0, stream>>>(a_fm, wt_fm, scales, out);
}